// Round 1
// baseline (7307.989 us; speedup 1.0000x reference)
//
#include <hip/hip_runtime.h>
#include <math.h>

#define NT 32768
#define DM 1024
#define NC 4096
#define CD 256

#define X_F4 (DM/4)   // 256 float4 per x row
#define W_F4 (CD/4)   // 64 float4 per W row
#define Z_F4 (CD/4)   // 64 float4 per z row
#define C_F4 (CD/4)   // 64 float4 per code row

// ---------------------------------------------------------------------------
// K0: half-norms of codebook rows. halfn[0] = +1e30 so code 0 never wins.
// One wave per code; 64 lanes x float4 = 256 elems.
// ---------------------------------------------------------------------------
__global__ __launch_bounds__(256) void k0_halfnorm(const float4* __restrict__ cb,
                                                   float* __restrict__ halfn) {
    int wid = threadIdx.x >> 6, lane = threadIdx.x & 63;
    int code = blockIdx.x * 4 + wid;
    float4 c = cb[(size_t)code * C_F4 + lane];
    float ss = c.x*c.x + c.y*c.y + c.z*c.z + c.w*c.w;
    #pragma unroll
    for (int m = 32; m >= 1; m >>= 1) ss += __shfl_xor(ss, m, 64);
    if (lane == 0) halfn[code] = (code == 0) ? 1e30f : 0.5f * ss;
}

// ---------------------------------------------------------------------------
// K1: z_pre = x @ W_down   (bias added in K1b)
// Block tile 128 rows x 64 cols, 256 threads, per-thread 8 rows x 4 cols.
// fp32 quad-dot products accumulated per 32-k chunk, folded into f64 acc
// (keeps z error ~1e-7 abs so downstream argmin isn't perturbed).
// LDS: A swizzled (xor by row-group) for conflict-free b128 reads.
// ---------------------------------------------------------------------------
__global__ __launch_bounds__(256) void k1_gemm1(const float4* __restrict__ X,
                                                const float4* __restrict__ W,
                                                float4* __restrict__ Zp) {
    __shared__ float4 As[1024];  // 128 rows x 8 f4 (32 k), swizzled
    __shared__ float4 Bs[512];   // 32 k x 16 f4 (64 cols)

    int tid  = threadIdx.x;
    int wid  = tid >> 6, lane = tid & 63;
    int tg   = ((wid & 1) << 3) | (lane & 7);    // 0..15 row-group (8 rows)
    int cg   = ((wid >> 1) << 3) | (lane >> 3);  // 0..15 col-group (4 cols = 1 f4)
    int mb   = blockIdx.x >> 2, nb = blockIdx.x & 3;
    int m0   = mb * 128;
    int n0v  = nb * 16;                          // f4 col base

    double dacc[8][4];
    #pragma unroll
    for (int i = 0; i < 8; ++i)
        #pragma unroll
        for (int j = 0; j < 4; ++j) dacc[i][j] = 0.0;

    for (int kt = 0; kt < 32; ++kt) {
        __syncthreads();
        #pragma unroll
        for (int jj = 0; jj < 4; ++jj) {
            int v = tid + 256 * jj;
            int row = v >> 3, kv4 = v & 7;
            As[row * 8 + (kv4 ^ ((row >> 3) & 7))] =
                X[(size_t)(m0 + row) * X_F4 + kt * 8 + kv4];
        }
        #pragma unroll
        for (int jj = 0; jj < 2; ++jj) {
            int v = tid + 256 * jj;
            int kk = v >> 4, cv4 = v & 15;
            Bs[kk * 16 + cv4] = W[(size_t)(kt * 32 + kk) * W_F4 + n0v + cv4];
        }
        __syncthreads();

        float facc[8][4];
        #pragma unroll
        for (int i = 0; i < 8; ++i)
            #pragma unroll
            for (int j = 0; j < 4; ++j) facc[i][j] = 0.0f;

        #pragma unroll
        for (int q = 0; q < 8; ++q) {
            float4 a[8], b[4];
            #pragma unroll
            for (int i = 0; i < 8; ++i)
                a[i] = As[(tg * 8 + i) * 8 + (q ^ (tg & 7))];
            #pragma unroll
            for (int p = 0; p < 4; ++p)
                b[p] = Bs[(q * 4 + p) * 16 + cg];
            #pragma unroll
            for (int i = 0; i < 8; ++i) {
                facc[i][0] += a[i].x*b[0].x + a[i].y*b[1].x + a[i].z*b[2].x + a[i].w*b[3].x;
                facc[i][1] += a[i].x*b[0].y + a[i].y*b[1].y + a[i].z*b[2].y + a[i].w*b[3].y;
                facc[i][2] += a[i].x*b[0].z + a[i].y*b[1].z + a[i].z*b[2].z + a[i].w*b[3].z;
                facc[i][3] += a[i].x*b[0].w + a[i].y*b[1].w + a[i].z*b[2].w + a[i].w*b[3].w;
            }
        }
        #pragma unroll
        for (int i = 0; i < 8; ++i)
            #pragma unroll
            for (int j = 0; j < 4; ++j) dacc[i][j] += (double)facc[i][j];
    }

    #pragma unroll
    for (int i = 0; i < 8; ++i) {
        int row = m0 + tg * 8 + i;
        float4 o;
        o.x = (float)dacc[i][0]; o.y = (float)dacc[i][1];
        o.z = (float)dacc[i][2]; o.w = (float)dacc[i][3];
        Zp[(size_t)row * Z_F4 + n0v + cg] = o;
    }
}

// ---------------------------------------------------------------------------
// K1b: z = (z_pre + b) / (||z_pre + b|| + 1e-6), in place on d_out z slot.
// One wave per token; norm accumulated in f64.
// ---------------------------------------------------------------------------
__global__ __launch_bounds__(256) void k1b_norm(float4* __restrict__ Z,
                                                const float4* __restrict__ bias) {
    int wid = threadIdx.x >> 6, lane = threadIdx.x & 63;
    int t = blockIdx.x * 4 + wid;
    float4 b = bias[lane];
    float4 z = Z[(size_t)t * Z_F4 + lane];
    z.x += b.x; z.y += b.y; z.z += b.z; z.w += b.w;
    double ss = (double)z.x*z.x + (double)z.y*z.y + (double)z.z*z.z + (double)z.w*z.w;
    #pragma unroll
    for (int m = 32; m >= 1; m >>= 1) ss += __shfl_xor(ss, m, 64);
    float inv = 1.0f / ((float)sqrt(ss) + 1e-6f);
    z.x *= inv; z.y *= inv; z.z *= inv; z.w *= inv;
    Z[(size_t)t * Z_F4 + lane] = z;
}

// ---------------------------------------------------------------------------
// K2: fp32 score GEMM + per-token running top-2 (score = z.c - 0.5||c||^2).
// Block: 64 tokens, loops over 16 tiles of 256 codes; per-thread 8 tok x 8
// codes; K staged in 32-wide chunks; XOR-swizzled f4 LDS, conflict-free b128.
// Emits top-2 candidate indices per token for f64 re-ranking in K3.
// ---------------------------------------------------------------------------
__global__ __launch_bounds__(256) void k2_scores(const float4* __restrict__ Z,
                                                 const float4* __restrict__ Cb,
                                                 const float4* __restrict__ halfn4,
                                                 int2* __restrict__ cands) {
    __shared__ float4 Zs[512];    // 64 tok x 8 f4 (32 k), swizzled
    __shared__ float4 Cs[2048];   // 256 codes x 8 f4 (32 k), swizzled; reused as merge buf

    int tid = threadIdx.x;
    int tg = tid & 7;        // token group: 8 tokens each
    int cg = tid >> 3;       // code group 0..31: 8 codes each
    int t0 = blockIdx.x * 64;

    float b1[8], b2[8], i1f[8], i2f[8];
    #pragma unroll
    for (int i = 0; i < 8; ++i) { b1[i] = -INFINITY; b2[i] = -INFINITY; i1f[i] = 0.0f; i2f[i] = 0.0f; }

    for (int ct = 0; ct < 16; ++ct) {
        float acc[8][8];
        #pragma unroll
        for (int i = 0; i < 8; ++i)
            #pragma unroll
            for (int j = 0; j < 8; ++j) acc[i][j] = 0.0f;

        for (int kc = 0; kc < 8; ++kc) {
            __syncthreads();
            #pragma unroll
            for (int jj = 0; jj < 2; ++jj) {
                int v = tid + 256 * jj;
                int tok = v >> 3, kv4 = v & 7;
                Zs[tok * 8 + (kv4 ^ ((tok >> 3) & 7))] =
                    Z[(size_t)(t0 + tok) * Z_F4 + kc * 8 + kv4];
            }
            #pragma unroll
            for (int jj = 0; jj < 8; ++jj) {
                int v = tid + 256 * jj;
                int code = v >> 3, kv4 = v & 7;
                Cs[code * 8 + (kv4 ^ ((code >> 3) & 7))] =
                    Cb[(size_t)(ct * 256 + code) * C_F4 + kc * 8 + kv4];
            }
            __syncthreads();

            #pragma unroll
            for (int q = 0; q < 8; ++q) {
                float4 a[8], b[8];
                #pragma unroll
                for (int i = 0; i < 8; ++i)
                    a[i] = Zs[(tg * 8 + i) * 8 + (q ^ (tg & 7))];
                #pragma unroll
                for (int j = 0; j < 8; ++j)
                    b[j] = Cs[(cg * 8 + j) * 8 + (q ^ (cg & 7))];
                #pragma unroll
                for (int i = 0; i < 8; ++i)
                    #pragma unroll
                    for (int j = 0; j < 8; ++j)
                        acc[i][j] += a[i].x*b[j].x + a[i].y*b[j].y + a[i].z*b[j].z + a[i].w*b[j].w;
            }
        }

        float4 h0 = halfn4[ct * 64 + cg * 2];
        float4 h1 = halfn4[ct * 64 + cg * 2 + 1];
        float hn[8] = {h0.x, h0.y, h0.z, h0.w, h1.x, h1.y, h1.z, h1.w};
        #pragma unroll
        for (int j = 0; j < 8; ++j) {
            float idxf = (float)(ct * 256 + cg * 8 + j);
            #pragma unroll
            for (int i = 0; i < 8; ++i) {
                float s = acc[i][j] - hn[j];
                if (s > b1[i])      { b2[i] = b1[i]; i2f[i] = i1f[i]; b1[i] = s; i1f[i] = idxf; }
                else if (s > b2[i]) { b2[i] = s; i2f[i] = idxf; }
            }
        }
    }

    // Cross-thread merge of top-2 over the 32 code-groups sharing each token.
    __syncthreads();
    float2* M = (float2*)Cs;  // [64 tok][32 cg][2] = 4096 float2 = 32 KB
    #pragma unroll
    for (int i = 0; i < 8; ++i) {
        int tok = tg * 8 + i;
        M[(tok * 32 + cg) * 2 + 0] = make_float2(b1[i], i1f[i]);
        M[(tok * 32 + cg) * 2 + 1] = make_float2(b2[i], i2f[i]);
    }
    __syncthreads();
    if (tid < 64) {
        int tok = tid;
        float s1 = -INFINITY, s2 = -INFINITY, x1 = 0.0f, x2 = 0.0f;
        for (int c = 0; c < 32; ++c) {
            #pragma unroll
            for (int e = 0; e < 2; ++e) {
                float2 ee = M[(tok * 32 + c) * 2 + e];
                if ((ee.x > s1) || (ee.x == s1 && ee.y < x1)) {
                    s2 = s1; x2 = x1; s1 = ee.x; x1 = ee.y;
                } else if ((ee.x > s2) || (ee.x == s2 && ee.y < x2)) {
                    s2 = ee.x; x2 = ee.y;
                }
            }
        }
        cands[t0 + tok] = make_int2((int)x1, (int)x2);
    }
}

// ---------------------------------------------------------------------------
// K3: f64 re-rank of the two candidates (tie -> lower index, matching
// jnp.argmin first-min semantics), write index (as float) + gather hard code.
// One wave per token.
// ---------------------------------------------------------------------------
__global__ __launch_bounds__(256) void k3_refine(const float4* __restrict__ Z,
                                                 const float4* __restrict__ Cb,
                                                 const int2* __restrict__ cands,
                                                 float* __restrict__ idxOut,
                                                 float4* __restrict__ hardOut) {
    int wid = threadIdx.x >> 6, lane = threadIdx.x & 63;
    int t = blockIdx.x * 4 + wid;
    int2 cd = cands[t];
    int cc[2] = {cd.x, cd.y};
    float4 z = Z[(size_t)t * Z_F4 + lane];
    double s[2];
    #pragma unroll
    for (int e = 0; e < 2; ++e) {
        float4 c = Cb[(size_t)cc[e] * C_F4 + lane];
        double dot = (double)z.x*c.x + (double)z.y*c.y + (double)z.z*c.z + (double)z.w*c.w;
        double nrm = (double)c.x*c.x + (double)c.y*c.y + (double)c.z*c.z + (double)c.w*c.w;
        #pragma unroll
        for (int m = 32; m >= 1; m >>= 1) {
            dot += __shfl_xor(dot, m, 64);
            nrm += __shfl_xor(nrm, m, 64);
        }
        s[e] = dot - 0.5 * nrm;
    }
    int win;
    if (s[0] > s[1])      win = cc[0];
    else if (s[1] > s[0]) win = cc[1];
    else                  win = min(cc[0], cc[1]);
    if (lane == 0) idxOut[t] = (float)win;
    hardOut[(size_t)t * C_F4 + lane] = Cb[(size_t)win * C_F4 + lane];
}

// ---------------------------------------------------------------------------
extern "C" void kernel_launch(void* const* d_in, const int* in_sizes, int n_in,
                              void* d_out, int out_size, void* d_ws, size_t ws_size,
                              hipStream_t stream) {
    const float* x  = (const float*)d_in[0];   // 32768 x 1024
    const float* cb = (const float*)d_in[1];   // 4096 x 256
    const float* w  = (const float*)d_in[2];   // 1024 x 256
    const float* bd = (const float*)d_in[3];   // 256

    float* zOut    = (float*)d_out;                    // 32768 x 256
    float* idxOut  = zOut + (size_t)NT * CD;           // 32768 (stored as float values)
    float* hardOut = idxOut + NT;                      // 32768 x 256

    float* halfn = (float*)d_ws;                       // 4096 floats (16 KB)
    int2*  cands = (int2*)((char*)d_ws + 16384);       // 32768 int2 (256 KB)

    k0_halfnorm<<<NC / 4, 256, 0, stream>>>((const float4*)cb, halfn);
    k1_gemm1<<<(NT / 128) * (CD / 64), 256, 0, stream>>>((const float4*)x,
                                                         (const float4*)w,
                                                         (float4*)zOut);
    k1b_norm<<<NT / 4, 256, 0, stream>>>((float4*)zOut, (const float4*)bd);
    k2_scores<<<NT / 64, 256, 0, stream>>>((const float4*)zOut, (const float4*)cb,
                                           (const float4*)halfn, cands);
    k3_refine<<<NT / 4, 256, 0, stream>>>((const float4*)zOut, (const float4*)cb,
                                          cands, idxOut, (float4*)hardOut);
}

// Round 2
// 822.474 us; speedup vs baseline: 8.8854x; 8.8854x over previous
//
#include <hip/hip_runtime.h>
#include <math.h>
#include <stdint.h>

#define NT 32768
#define DM 1024
#define NC 4096
#define CD 256

#define X_F4 (DM/4)
#define W_F4 (CD/4)
#define Z_F4 (CD/4)
#define C_F4 (CD/4)

typedef __attribute__((ext_vector_type(8))) short bf16x8;
typedef __attribute__((ext_vector_type(4))) float floatx4;

__device__ __forceinline__ unsigned short f2bf(float f) {
    union { float f; uint32_t u; } v; v.f = f;
    uint32_t u = v.u;
    u += 0x7FFFu + ((u >> 16) & 1u);   // RN-even
    return (unsigned short)(u >> 16);
}

// ---------------------------------------------------------------------------
// K0: per-code prep: hn2[code] = 0.5*||c||^2 - 2  (key shift makes s' in
// [0.5,2.5] > 0 so u32 bit-compare == float compare), plus bf16 codebook.
// ---------------------------------------------------------------------------
__global__ __launch_bounds__(256) void k0_prep(const float4* __restrict__ cb,
                                               float* __restrict__ hn2,
                                               ushort* __restrict__ cbb) {
    int wid = threadIdx.x >> 6, lane = threadIdx.x & 63;
    int code = blockIdx.x * 4 + wid;
    float4 c = cb[(size_t)code * C_F4 + lane];
    ushort4 h;
    h.x = f2bf(c.x); h.y = f2bf(c.y); h.z = f2bf(c.z); h.w = f2bf(c.w);
    ((ushort4*)cbb)[(size_t)code * 64 + lane] = h;
    float ss = c.x*c.x + c.y*c.y + c.z*c.z + c.w*c.w;
    #pragma unroll
    for (int m = 32; m >= 1; m >>= 1) ss += __shfl_xor(ss, m, 64);
    if (lane == 0) hn2[code] = 0.5f * ss - 2.0f;
}

// ---------------------------------------------------------------------------
// K1: z_pre = x @ W_down (unchanged from round 1 — proven; next-round target)
// ---------------------------------------------------------------------------
__global__ __launch_bounds__(256) void k1_gemm1(const float4* __restrict__ X,
                                                const float4* __restrict__ W,
                                                float4* __restrict__ Zp) {
    __shared__ float4 As[1024];
    __shared__ float4 Bs[512];

    int tid  = threadIdx.x;
    int wid  = tid >> 6, lane = tid & 63;
    int tg   = ((wid & 1) << 3) | (lane & 7);
    int cg   = ((wid >> 1) << 3) | (lane >> 3);
    int mb   = blockIdx.x >> 2, nb = blockIdx.x & 3;
    int m0   = mb * 128;
    int n0v  = nb * 16;

    double dacc[8][4];
    #pragma unroll
    for (int i = 0; i < 8; ++i)
        #pragma unroll
        for (int j = 0; j < 4; ++j) dacc[i][j] = 0.0;

    for (int kt = 0; kt < 32; ++kt) {
        __syncthreads();
        #pragma unroll
        for (int jj = 0; jj < 4; ++jj) {
            int v = tid + 256 * jj;
            int row = v >> 3, kv4 = v & 7;
            As[row * 8 + (kv4 ^ ((row >> 3) & 7))] =
                X[(size_t)(m0 + row) * X_F4 + kt * 8 + kv4];
        }
        #pragma unroll
        for (int jj = 0; jj < 2; ++jj) {
            int v = tid + 256 * jj;
            int kk = v >> 4, cv4 = v & 15;
            Bs[kk * 16 + cv4] = W[(size_t)(kt * 32 + kk) * W_F4 + n0v + cv4];
        }
        __syncthreads();

        float facc[8][4];
        #pragma unroll
        for (int i = 0; i < 8; ++i)
            #pragma unroll
            for (int j = 0; j < 4; ++j) facc[i][j] = 0.0f;

        #pragma unroll
        for (int q = 0; q < 8; ++q) {
            float4 a[8], b[4];
            #pragma unroll
            for (int i = 0; i < 8; ++i)
                a[i] = As[(tg * 8 + i) * 8 + (q ^ (tg & 7))];
            #pragma unroll
            for (int p = 0; p < 4; ++p)
                b[p] = Bs[(q * 4 + p) * 16 + cg];
            #pragma unroll
            for (int i = 0; i < 8; ++i) {
                facc[i][0] += a[i].x*b[0].x + a[i].y*b[1].x + a[i].z*b[2].x + a[i].w*b[3].x;
                facc[i][1] += a[i].x*b[0].y + a[i].y*b[1].y + a[i].z*b[2].y + a[i].w*b[3].y;
                facc[i][2] += a[i].x*b[0].z + a[i].y*b[1].z + a[i].z*b[2].z + a[i].w*b[3].z;
                facc[i][3] += a[i].x*b[0].w + a[i].y*b[1].w + a[i].z*b[2].w + a[i].w*b[3].w;
            }
        }
        #pragma unroll
        for (int i = 0; i < 8; ++i)
            #pragma unroll
            for (int j = 0; j < 4; ++j) dacc[i][j] += (double)facc[i][j];
    }

    #pragma unroll
    for (int i = 0; i < 8; ++i) {
        int row = m0 + tg * 8 + i;
        float4 o;
        o.x = (float)dacc[i][0]; o.y = (float)dacc[i][1];
        o.z = (float)dacc[i][2]; o.w = (float)dacc[i][3];
        Zp[(size_t)row * Z_F4 + n0v + cg] = o;
    }
}

// ---------------------------------------------------------------------------
// K1b: z = (z_pre + b) / (||z_pre + b|| + 1e-6) (unchanged)
// ---------------------------------------------------------------------------
__global__ __launch_bounds__(256) void k1b_norm(float4* __restrict__ Z,
                                                const float4* __restrict__ bias) {
    int wid = threadIdx.x >> 6, lane = threadIdx.x & 63;
    int t = blockIdx.x * 4 + wid;
    float4 b = bias[lane];
    float4 z = Z[(size_t)t * Z_F4 + lane];
    z.x += b.x; z.y += b.y; z.z += b.z; z.w += b.w;
    double ss = (double)z.x*z.x + (double)z.y*z.y + (double)z.z*z.z + (double)z.w*z.w;
    #pragma unroll
    for (int m = 32; m >= 1; m >>= 1) ss += __shfl_xor(ss, m, 64);
    float inv = 1.0f / ((float)sqrt(ss) + 1e-6f);
    z.x *= inv; z.y *= inv; z.z *= inv; z.w *= inv;
    Z[(size_t)t * Z_F4 + lane] = z;
}

// ---------------------------------------------------------------------------
// K2: bf16 MFMA candidate scoring.
// Block = 4 waves, 64 tokens. Each wave: same 64 tokens (A in 128 VGPRs,
// loop-invariant, converted f32->bf16 in-register), code quarter w of each
// 64-code tile. 64 tiles. Per tile per wave: 8 ds_read_b128 (XOR-swizzled
// LDS) : 32 MFMA. Scores packed into sortable u32 keys (15 high float bits +
// 6-bit tile id); per-lane running top-2 via 3x max/min; end: LDS merge ->
// global top-4 per token -> cands (int4). Code 0 replaced by code 1 at
// staging (excluded later in K3).
// ---------------------------------------------------------------------------
__global__ __launch_bounds__(256, 2) void k2_mfma(const float* __restrict__ Z,
                                                  const ushort* __restrict__ Cbb,
                                                  const float* __restrict__ hn2g,
                                                  int4* __restrict__ cands) {
    __shared__ __align__(16) char lds[32768 + 256];  // B tile + hn2; merge reuses B

    int tid  = threadIdx.x;
    int w    = tid >> 6;         // wave id = code quarter
    int lane = tid & 63;
    int c    = lane & 15, q = lane >> 4;
    int t0   = blockIdx.x * 64;

    // ---- A fragments: 4 mi x 8 ks, f32 -> bf16 in-register
    bf16x8 A[4][8];
    #pragma unroll
    for (int mi = 0; mi < 4; ++mi) {
        #pragma unroll
        for (int ks = 0; ks < 8; ++ks) {
            const float* zp = Z + (size_t)(t0 + mi * 16 + c) * CD + ks * 32 + q * 8;
            float4 f0 = *(const float4*)zp;
            float4 f1 = *(const float4*)(zp + 4);
            bf16x8 a;
            a[0] = (short)f2bf(f0.x); a[1] = (short)f2bf(f0.y);
            a[2] = (short)f2bf(f0.z); a[3] = (short)f2bf(f0.w);
            a[4] = (short)f2bf(f1.x); a[5] = (short)f2bf(f1.y);
            a[6] = (short)f2bf(f1.z); a[7] = (short)f2bf(f1.w);
            A[mi][ks] = a;
        }
    }

    // ---- per-lane B read addresses (invariant across tiles)
    int baddr[8];
    #pragma unroll
    for (int ks = 0; ks < 8; ++ks)
        baddr[ks] = (w * 16 + c) * 512 + ((((ks * 4 + q) ^ c)) << 4);
    int hnaddr = 32768 + (w * 16 + c) * 4;

    auto issue_loads = [&](int ct, bf16x8* g, float& hnr) {
        #pragma unroll
        for (int jj = 0; jj < 8; ++jj) {
            int v = jj * 256 + tid;
            int row = v >> 5, ch = v & 31;
            int grow = ct * 64 + row; if (grow < 1) grow = 1;   // exclude code 0
            g[jj] = *(const bf16x8*)(Cbb + (size_t)grow * CD + ch * 8);
        }
        if (tid < 64) {
            int gc = ct * 64 + tid; if (gc < 1) gc = 1;
            hnr = hn2g[gc];
        }
    };
    auto write_lds = [&](const bf16x8* g, float hnr) {
        #pragma unroll
        for (int jj = 0; jj < 8; ++jj) {
            int v = jj * 256 + tid;
            int row = v >> 5, ch = v & 31;
            *(bf16x8*)(lds + row * 512 + ((ch ^ (row & 15)) << 4)) = g[jj];
        }
        if (tid < 64) *(float*)(lds + 32768 + tid * 4) = hnr;
    };

    uint32_t K1[16], K2[16];
    #pragma unroll
    for (int i = 0; i < 16; ++i) { K1[i] = 0u; K2[i] = 0u; }

    bf16x8 g[8]; float hnr = 0.0f;
    issue_loads(0, g, hnr);
    write_lds(g, hnr);

    for (int ct = 0; ct < 64; ++ct) {
        __syncthreads();
        bf16x8 g2[8]; float hnr2 = 0.0f;
        if (ct < 63) issue_loads(ct + 1, g2, hnr2);

        floatx4 C[4];
        #pragma unroll
        for (int mi = 0; mi < 4; ++mi) C[mi] = (floatx4){0.f, 0.f, 0.f, 0.f};

        #pragma unroll
        for (int ks = 0; ks < 8; ++ks) {
            bf16x8 Bf = *(const bf16x8*)(lds + baddr[ks]);
            #pragma unroll
            for (int mi = 0; mi < 4; ++mi)
                C[mi] = __builtin_amdgcn_mfma_f32_16x16x32_bf16(A[mi][ks], Bf, C[mi], 0, 0, 0);
        }

        float hv = *(const float*)(lds + hnaddr);
        #pragma unroll
        for (int mi = 0; mi < 4; ++mi) {
            #pragma unroll
            for (int r = 0; r < 4; ++r) {
                float sp = C[mi][r] - hv;              // = z.c + 1.5, in [0.5,2.5]
                union { float f; uint32_t u; } uv; uv.f = sp;
                uint32_t key = (uv.u & 0xFFFFFFC0u) | (uint32_t)ct;
                int i = mi * 4 + r;
                uint32_t lo = key < K1[i] ? key : K1[i];
                K1[i] = key > K1[i] ? key : K1[i];
                K2[i] = lo > K2[i] ? lo : K2[i];
            }
        }

        __syncthreads();
        if (ct < 63) write_lds(g2, hnr2);
    }

    // ---- merge: per token, 4 waves x 16 lanes x top-2 = 128 keys -> top-4
    __syncthreads();
    uint32_t* M = (uint32_t*)lds;   // [tok][w][c][2]
    #pragma unroll
    for (int mi = 0; mi < 4; ++mi) {
        #pragma unroll
        for (int r = 0; r < 4; ++r) {
            int tok = mi * 16 + q * 4 + r;
            int base = ((tok * 4 + w) * 16 + c) * 2;
            M[base]     = K1[mi * 4 + r];
            M[base + 1] = K2[mi * 4 + r];
        }
    }
    __syncthreads();
    if (tid < 64) {
        int tok = tid;
        uint32_t bk0 = 0, bk1 = 0, bk2 = 0, bk3 = 0;
        int      bp0 = 0, bp1 = 0, bp2 = 0, bp3 = 0;
        for (int e = 0; e < 128; ++e) {
            uint32_t key = M[tok * 128 + e];
            int pos = e >> 1;   // = w*16 + c
            if (key > bk0) {
                bk3 = bk2; bp3 = bp2; bk2 = bk1; bp2 = bp1;
                bk1 = bk0; bp1 = bp0; bk0 = key; bp0 = pos;
            } else if (key > bk1) {
                bk3 = bk2; bp3 = bp2; bk2 = bk1; bp2 = bp1; bk1 = key; bp1 = pos;
            } else if (key > bk2) {
                bk3 = bk2; bp3 = bp2; bk2 = key; bp2 = pos;
            } else if (key > bk3) {
                bk3 = key; bp3 = pos;
            }
        }
        int4 out;
        out.x = (int)(bk0 & 63u) * 64 + bp0;
        out.y = (int)(bk1 & 63u) * 64 + bp1;
        out.z = (int)(bk2 & 63u) * 64 + bp2;
        out.w = (int)(bk3 & 63u) * 64 + bp3;
        cands[t0 + tok] = out;
    }
}

// ---------------------------------------------------------------------------
// K3: f64 re-rank of 4 candidates (code 0 invalid; ties -> lowest index),
// write index (as float) + gather hard code. One wave per token.
// ---------------------------------------------------------------------------
__global__ __launch_bounds__(256) void k3_refine(const float4* __restrict__ Z,
                                                 const float4* __restrict__ Cb,
                                                 const int4* __restrict__ cands,
                                                 float* __restrict__ idxOut,
                                                 float4* __restrict__ hardOut) {
    int wid = threadIdx.x >> 6, lane = threadIdx.x & 63;
    int t = blockIdx.x * 4 + wid;
    int4 cd = cands[t];
    int cc[4] = {cd.x, cd.y, cd.z, cd.w};
    float4 z = Z[(size_t)t * Z_F4 + lane];
    double best = -1.0e300;
    int bi = NC;   // sentinel
    #pragma unroll
    for (int e = 0; e < 4; ++e) {
        int idx = cc[e];
        float4 cf = Cb[(size_t)idx * C_F4 + lane];
        double dot = (double)z.x*cf.x + (double)z.y*cf.y + (double)z.z*cf.z + (double)z.w*cf.w;
        double nrm = (double)cf.x*cf.x + (double)cf.y*cf.y + (double)cf.z*cf.z + (double)cf.w*cf.w;
        #pragma unroll
        for (int m = 32; m >= 1; m >>= 1) {
            dot += __shfl_xor(dot, m, 64);
            nrm += __shfl_xor(nrm, m, 64);
        }
        double s = dot - 0.5 * nrm;
        if (idx >= 1 && (s > best || (s == best && idx < bi))) { best = s; bi = idx; }
    }
    if (lane == 0) idxOut[t] = (float)bi;
    hardOut[(size_t)t * C_F4 + lane] = Cb[(size_t)bi * C_F4 + lane];
}

// ---------------------------------------------------------------------------
extern "C" void kernel_launch(void* const* d_in, const int* in_sizes, int n_in,
                              void* d_out, int out_size, void* d_ws, size_t ws_size,
                              hipStream_t stream) {
    const float* x  = (const float*)d_in[0];   // 32768 x 1024
    const float* cb = (const float*)d_in[1];   // 4096 x 256
    const float* w  = (const float*)d_in[2];   // 1024 x 256
    const float* bd = (const float*)d_in[3];   // 256

    float* zOut    = (float*)d_out;                    // 32768 x 256
    float* idxOut  = zOut + (size_t)NT * CD;           // 32768 (as float values)
    float* hardOut = idxOut + NT;                      // 32768 x 256

    float*  hn2   = (float*)d_ws;                            // 16 KB
    int4*   cands = (int4*)((char*)d_ws + 16384);            // 512 KB
    ushort* cbb   = (ushort*)((char*)d_ws + 16384 + 524288); // 2 MB bf16 codebook

    k0_prep<<<NC / 4, 256, 0, stream>>>((const float4*)cb, hn2, cbb);
    k1_gemm1<<<(NT / 128) * (CD / 64), 256, 0, stream>>>((const float4*)x,
                                                         (const float4*)w,
                                                         (float4*)zOut);
    k1b_norm<<<NT / 4, 256, 0, stream>>>((float4*)zOut, (const float4*)bd);
    k2_mfma<<<NT / 64, 256, 0, stream>>>(zOut, cbb, hn2, cands);
    k3_refine<<<NT / 4, 256, 0, stream>>>((const float4*)zOut, (const float4*)cb,
                                          cands, idxOut, (float4*)hardOut);
}